// Round 7
// baseline (386.313 us; speedup 1.0000x reference)
//
#include <hip/hip_runtime.h>

typedef unsigned short u16;
typedef unsigned int u32;
typedef __attribute__((ext_vector_type(8))) __bf16 bf16x8;
typedef __attribute__((ext_vector_type(4))) float f32x4;

__device__ __forceinline__ u16 f2bf(float f) {
  unsigned u = __float_as_uint(f);
  u += 0x7FFFu + ((u >> 16) & 1u);   // round-to-nearest-even
  return (u16)(u >> 16);
}

// gfx950 packed f32x2 -> bf16x2 (lo=a, hi=b)
__device__ __forceinline__ u32 pk_bf16(float a, float b) {
  u32 r;
  asm("v_cvt_pk_bf16_f32 %0, %1, %2" : "=v"(r) : "v"(a), "v"(b));
  return r;
}
__device__ __forceinline__ float fast_exp2(float x) { return __builtin_amdgcn_exp2f(x); }
__device__ __forceinline__ float fast_rcp(float x) { return __builtin_amdgcn_rcpf(x); }

// ---------------- merged f32 -> bf16 conversions (one dispatch) ----------------
__global__ void cvt_all(const float* __restrict__ x, const float* __restrict__ Wq,
                        const float* __restrict__ y, const float* __restrict__ Wkv,
                        const int* __restrict__ mask,
                        u16* __restrict__ Xb, u16* __restrict__ Wqb,
                        u16* __restrict__ Yb, u16* __restrict__ Wkvb) {
  int i = blockIdx.x * 256 + threadIdx.x;
  const float4* src;
  u16* dst;
  int j;
  float sc;
  if (i < 2097152) {
    j = i; src = (const float4*)x; dst = Xb;
    sc = (mask[i >> 8] != 0) ? 1.0f : 0.0f;  // masked q-rows -> Q=0 -> uniform softmax
  } else if (i < 2359296) {
    j = i - 2097152; src = (const float4*)Wq; dst = Wqb;
    sc = 0.18033688f;  // d^-0.5 * log2(e): exp via v_exp_f32 base-2
  } else if (i < 3145728) {
    j = i - 2359296; src = (const float4*)y; dst = Yb;
    sc = 1.0f;
  } else {
    j = i - 3145728; src = (const float4*)Wkv; dst = Wkvb;
    sc = 1.0f;
  }
  float4 v = src[j];
  ushort4 o;
  o.x = f2bf(v.x * sc);
  o.y = f2bf(v.y * sc);
  o.z = f2bf(v.z * sc);
  o.w = f2bf(v.w * sc);
  ((ushort4*)dst)[j] = o;
}

// ---------------- bf16 GEMM: C[M,N] = A[M,K] * B[N,K]^T (R4-proven) ----------------
__global__ __launch_bounds__(256) void gemm_bt(const u16* __restrict__ A,
                                               const u16* __restrict__ B,
                                               u16* __restrict__ C,
                                               int M, int N, int K) {
  __shared__ __align__(16) u16 sA[128 * 32];
  __shared__ __align__(16) u16 sB[128 * 32];
  const int t = threadIdx.x;
  const int wave = t >> 6;
  const int lane = t & 63;
  const int wm = (wave >> 1) * 64;
  const int wn = (wave & 1) * 64;
  const int fr = lane & 15;
  const int quad = lane >> 4;
  const int fk = quad * 8;
  const int sr = lane >> 2;
  const int sc = (lane & 3) * 8;

  f32x4 acc[4][4];
  const f32x4 z4 = {0.f, 0.f, 0.f, 0.f};
#pragma unroll
  for (int i = 0; i < 4; ++i)
#pragma unroll
    for (int j = 0; j < 4; ++j) acc[i][j] = z4;

  const u16* Abase = A + (size_t)blockIdx.x * 128 * K;
  const u16* Bbase = B + (size_t)blockIdx.y * 128 * K;

  for (int k0 = 0; k0 < K; k0 += 32) {
#pragma unroll
    for (int q = 0; q < 2; ++q) {
      const int chunk = wave * 2 + q;
      const int row = chunk * 16 + sr;
      __builtin_amdgcn_global_load_lds(
          (__attribute__((address_space(1))) void*)(Abase + (size_t)row * K + k0 + sc),
          (__attribute__((address_space(3))) void*)(sA + chunk * 512), 16, 0, 0);
      __builtin_amdgcn_global_load_lds(
          (__attribute__((address_space(1))) void*)(Bbase + (size_t)row * K + k0 + sc),
          (__attribute__((address_space(3))) void*)(sB + chunk * 512), 16, 0, 0);
    }
    __syncthreads();
    bf16x8 af[4], bfv[4];
#pragma unroll
    for (int i = 0; i < 4; ++i)
      af[i] = *(const bf16x8*)(sA + (wm + i * 16 + fr) * 32 + fk);
#pragma unroll
    for (int j = 0; j < 4; ++j)
      bfv[j] = *(const bf16x8*)(sB + (wn + j * 16 + fr) * 32 + fk);
#pragma unroll
    for (int i = 0; i < 4; ++i)
#pragma unroll
      for (int j = 0; j < 4; ++j)
        acc[i][j] = __builtin_amdgcn_mfma_f32_16x16x32_bf16(af[i], bfv[j], acc[i][j], 0, 0, 0);
    __syncthreads();
  }

#pragma unroll
  for (int i = 0; i < 4; ++i)
#pragma unroll
    for (int j = 0; j < 4; ++j)
#pragma unroll
      for (int r = 0; r < 4; ++r) {
        const int row = blockIdx.x * 128 + wm + i * 16 + quad * 4 + r;
        const int col = blockIdx.y * 128 + wn + j * 16 + fr;
        C[(size_t)row * N + col] = f2bf(acc[i][j][r]);
      }
}

// ---------------- transpose V half of KV into Vt[b,h,d, sigma(N2)] ----------------
// sigma(k) = (k&~31) | (2*(k&15) + ((k>>4)&1)) -- matches attn's P dword packing.
// (R4-proven pair with attn's P layout.)
__global__ void transpose_v(const u16* __restrict__ KV, u16* __restrict__ Vt) {
  __shared__ u16 tile[64][66];
  const int t = threadIdx.x;
  const int rb = blockIdx.x * 64;
  const int h = blockIdx.y;
#pragma unroll
  for (int i = 0; i < 16; ++i) {
    int idx = i * 256 + t;
    int r = idx >> 6, c = idx & 63;
    tile[r][c] = KV[(size_t)(rb + r) * 2048 + 1024 + h * 64 + c];
  }
  __syncthreads();
  const int b = blockIdx.x >> 4;
  const int n2b = (blockIdx.x & 15) * 64;
#pragma unroll
  for (int i = 0; i < 16; ++i) {
    int idx = i * 256 + t;
    int dd = idx >> 6, n2 = idx & 63;
    int cperm = (n2 & 32) | (2 * (n2 & 15) + ((n2 >> 4) & 1));
    Vt[(size_t)((b * 16 + h) * 64 + dd) * 1024 + n2b + cperm] = tile[n2][dd];
  }
}

// ---------------- fused flash attention, BARRIER-FREE K-loop ----------------
// R4's exact data path, but K/V fragments are loaded DIRECTLY from global
// (each fragment = contiguous 16B/lane; 32 blocks per (b,h) are XCD-swizzled
// onto one L2 -> K/V chunks are cache-resident re-reads). The only LDS use is
// the wave-private P round-trip (per-wave in-order, needs no barrier), so the
// main loop has NO __syncthreads -> no vmcnt/lgkmcnt drain stalls (the
// measured 70%-stall limiter of R2/R4). LDS 17408 B.
__global__ __launch_bounds__(256, 3) void attn_kernel(
    const u16* __restrict__ Q, const u16* __restrict__ KV,
    const u16* __restrict__ Vt, float* __restrict__ Out) {
  __shared__ __align__(16) u16 sP[4][16 * 136];   // per-wave P [q][perm key]

  const int t = threadIdx.x;
  const int wave = t >> 6;
  const int lane = t & 63;
  const int g = blockIdx.x & 63;     // (b,h): same mod-64 -> same XCD L2
  const int qt = blockIdx.x >> 6;    // 0..15
  const int b = g >> 4;
  const int h = g & 15;
  const int q0 = qt * 128;
  const int fr = lane & 15;
  const int quad = lane >> 4;

  // Q A-fragments for both 64-row halves (kc-invariant)
  const u16* qbase = Q + (size_t)(b * 2048 + q0 + wave * 16 + fr) * 1024 + h * 64 + quad * 8;
  bf16x8 qa[2][2];
  qa[0][0] = *(const bf16x8*)(qbase);
  qa[0][1] = *(const bf16x8*)(qbase + 32);
  qa[1][0] = *(const bf16x8*)(qbase + (size_t)64 * 1024);
  qa[1][1] = *(const bf16x8*)(qbase + (size_t)64 * 1024 + 32);

  const f32x4 z4 = {0.f, 0.f, 0.f, 0.f};
  float lacc[2][4];              // per-lane l partials (reduced once at end)
  f32x4 o[2][4];
#pragma unroll
  for (int hh = 0; hh < 2; ++hh)
#pragma unroll
    for (int r = 0; r < 4; ++r) { lacc[hh][r] = 0.f; o[hh][r] = z4; }

  const u16* Kbase = KV + (size_t)(b * 1024) * 2048 + h * 64;         // row stride 2048
  const u16* Vbase = Vt + (size_t)((b * 16 + h) * 64) * 1024;        // row stride 1024
  u32* pw = (u32*)&sP[wave][0];            // dword pitch 68
  const u16* pb = (const u16*)&sP[wave][0];

  for (int kc = 0; kc < 8; ++kc) {
#pragma unroll
    for (int hh = 0; hh < 2; ++hh) {
      // QK^T: S[16 q x 128 keys]; K fragments direct from global (16B/lane)
      f32x4 s[8];
#pragma unroll
      for (int nt = 0; nt < 8; ++nt) {
        const u16* kr = Kbase + (size_t)(kc * 128 + nt * 16 + fr) * 2048 + quad * 8;
        bf16x8 b0 = *(const bf16x8*)(kr);
        bf16x8 b1 = *(const bf16x8*)(kr + 32);
        f32x4 zz = __builtin_amdgcn_mfma_f32_16x16x32_bf16(qa[hh][0], b0, z4, 0, 0, 0);
        s[nt] = __builtin_amdgcn_mfma_f32_16x16x32_bf16(qa[hh][1], b1, zz, 0, 0, 0);
      }

      // P = exp2(s) (log2e folded into Wq); per-lane l accumulation
#pragma unroll
      for (int nt = 0; nt < 8; ++nt)
#pragma unroll
        for (int r = 0; r < 4; ++r) {
          float p = fast_exp2(s[nt][r]);
          s[nt][r] = p;
          lacc[hh][r] += p;
        }

      // P -> LDS (wave-private slab, R4-proven layout):
      // dword (row, np*16+fr) = keys {32np+fr lo, 32np+16+fr hi} = perm pos 2fr(+1)
#pragma unroll
      for (int np = 0; np < 4; ++np)
#pragma unroll
        for (int r = 0; r < 4; ++r)
          pw[(quad * 4 + r) * 68 + np * 16 + fr] = pk_bf16(s[2 * np][r], s[2 * np + 1][r]);

      asm volatile("" ::: "memory");  // keep pa reads after pw writes (same-wave LDS is in-order)

      // PV over permuted keys; V fragments direct from global (permuted Vt)
#pragma unroll
      for (int ks = 0; ks < 4; ++ks) {
        bf16x8 pa = *(const bf16x8*)(pb + fr * 136 + ks * 32 + quad * 8);
#pragma unroll
        for (int nt = 0; nt < 4; ++nt) {
          const u16* vr = Vbase + (size_t)(nt * 16 + fr) * 1024 + kc * 128 + ks * 32 + quad * 8;
          bf16x8 vb = *(const bf16x8*)(vr);
          o[hh][nt] = __builtin_amdgcn_mfma_f32_16x16x32_bf16(pa, vb, o[hh][nt], 0, 0, 0);
        }
      }
      asm volatile("" ::: "memory");  // order next-half P writes after these P reads
    }
  }

  // epilogue: reduce l over the 16 fr lanes (exact sum, reordered), normalize, store
#pragma unroll
  for (int hh = 0; hh < 2; ++hh) {
    float inv[4];
#pragma unroll
    for (int r = 0; r < 4; ++r) {
      float v = lacc[hh][r];
      v += __shfl_xor(v, 1);
      v += __shfl_xor(v, 2);
      v += __shfl_xor(v, 4);
      v += __shfl_xor(v, 8);
      inv[r] = fast_rcp(v);
    }
#pragma unroll
    for (int nt = 0; nt < 4; ++nt)
#pragma unroll
      for (int r = 0; r < 4; ++r) {
        const int row = q0 + hh * 64 + wave * 16 + quad * 4 + r;
        const int col = h * 64 + nt * 16 + fr;
        Out[(size_t)(b * 2048 + row) * 1024 + col] = o[hh][nt][r] * inv[r];
      }
  }
}

// ---------------- launch (R4-proven config) ----------------
extern "C" void kernel_launch(void* const* d_in, const int* in_sizes, int n_in,
                              void* d_out, int out_size, void* d_ws, size_t ws_size,
                              hipStream_t stream) {
  (void)in_sizes; (void)n_in; (void)out_size; (void)ws_size;
  const float* x   = (const float*)d_in[0];   // [4,2048,1024]
  const float* y   = (const float*)d_in[1];   // [4,1024,768]
  const int*   msk = (const int*)d_in[2];     // [4,2048]
  const float* Wq  = (const float*)d_in[3];   // [1024,1024]
  const float* Wkv = (const float*)d_in[4];   // [2048,768]
  float* out = (float*)d_out;                 // [4,2048,1024] f32

  char* ws = (char*)d_ws;
  const size_t MB = 1024 * 1024;
  // High-water 51 MB (R4-proven layout).
  u16* Xb   = (u16*)(ws + 0);        // 16 MB [8192][1024] mask-folded (dead after gemm_q)
  u16* Wqb  = (u16*)(ws + 16 * MB);  //  2 MB [1024][1024] * d^-0.5 * log2e
  u16* Yb   = (u16*)(ws + 18 * MB);  //  6 MB [4096][768]
  u16* Wkvb = (u16*)(ws + 24 * MB);  //  3 MB [2048][768]
  u16* Qb   = (u16*)(ws + 27 * MB);  // 16 MB [8192][1024]
  u16* KVb  = (u16*)(ws + 0);        // 16 MB [4096][2048] (over dead Xb, after gemm_q)
  u16* Vtb  = (u16*)(ws + 43 * MB);  //  8 MB [4096][1024]

  cvt_all<<<13824, 256, 0, stream>>>(x, Wq, y, Wkv, msk, Xb, Wqb, Yb, Wkvb);
  gemm_bt<<<dim3(64, 8), 256, 0, stream>>>(Xb, Wqb, Qb, 8192, 1024, 1024);
  gemm_bt<<<dim3(32, 16), 256, 0, stream>>>(Yb, Wkvb, KVb, 4096, 2048, 768);
  transpose_v<<<dim3(64, 16), 256, 0, stream>>>(KVb, Vtb);
  attn_kernel<<<1024, 256, 0, stream>>>(Qb, KVb, Vtb, out);
}

// Round 8
// 270.068 us; speedup vs baseline: 1.4304x; 1.4304x over previous
//
#include <hip/hip_runtime.h>

typedef unsigned short u16;
typedef unsigned int u32;
typedef __attribute__((ext_vector_type(8))) __bf16 bf16x8;
typedef __attribute__((ext_vector_type(4))) float f32x4;

__device__ __forceinline__ u16 f2bf(float f) {
  unsigned u = __float_as_uint(f);
  u += 0x7FFFu + ((u >> 16) & 1u);   // round-to-nearest-even
  return (u16)(u >> 16);
}

// gfx950 packed f32x2 -> bf16x2 (lo=a, hi=b)
__device__ __forceinline__ u32 pk_bf16(float a, float b) {
  u32 r;
  asm("v_cvt_pk_bf16_f32 %0, %1, %2" : "=v"(r) : "v"(a), "v"(b));
  return r;
}
__device__ __forceinline__ float fast_exp2(float x) { return __builtin_amdgcn_exp2f(x); }
__device__ __forceinline__ float fast_rcp(float x) { return __builtin_amdgcn_rcpf(x); }

// ---------------- merged f32 -> bf16 conversions (one dispatch) ----------------
__global__ void cvt_all(const float* __restrict__ x, const float* __restrict__ Wq,
                        const float* __restrict__ y, const float* __restrict__ Wkv,
                        const int* __restrict__ mask,
                        u16* __restrict__ Xb, u16* __restrict__ Wqb,
                        u16* __restrict__ Yb, u16* __restrict__ Wkvb) {
  int i = blockIdx.x * 256 + threadIdx.x;
  const float4* src;
  u16* dst;
  int j;
  float sc;
  if (i < 2097152) {
    j = i; src = (const float4*)x; dst = Xb;
    sc = (mask[i >> 8] != 0) ? 1.0f : 0.0f;  // masked q-rows -> Q=0 -> uniform softmax
  } else if (i < 2359296) {
    j = i - 2097152; src = (const float4*)Wq; dst = Wqb;
    sc = 0.18033688f;  // d^-0.5 * log2(e): exp via v_exp_f32 base-2
  } else if (i < 3145728) {
    j = i - 2359296; src = (const float4*)y; dst = Yb;
    sc = 1.0f;
  } else {
    j = i - 3145728; src = (const float4*)Wkv; dst = Wkvb;
    sc = 1.0f;
  }
  float4 v = src[j];
  ushort4 o;
  o.x = f2bf(v.x * sc);
  o.y = f2bf(v.y * sc);
  o.z = f2bf(v.z * sc);
  o.w = f2bf(v.w * sc);
  ((ushort4*)dst)[j] = o;
}

// ---------------- bf16 GEMM: C[M,N] = A[M,K] * B[N,K]^T (R4-proven) ----------------
__global__ __launch_bounds__(256) void gemm_bt(const u16* __restrict__ A,
                                               const u16* __restrict__ B,
                                               u16* __restrict__ C,
                                               int M, int N, int K) {
  __shared__ __align__(16) u16 sA[128 * 32];
  __shared__ __align__(16) u16 sB[128 * 32];
  const int t = threadIdx.x;
  const int wave = t >> 6;
  const int lane = t & 63;
  const int wm = (wave >> 1) * 64;
  const int wn = (wave & 1) * 64;
  const int fr = lane & 15;
  const int quad = lane >> 4;
  const int fk = quad * 8;
  const int sr = lane >> 2;
  const int sc = (lane & 3) * 8;

  f32x4 acc[4][4];
  const f32x4 z4 = {0.f, 0.f, 0.f, 0.f};
#pragma unroll
  for (int i = 0; i < 4; ++i)
#pragma unroll
    for (int j = 0; j < 4; ++j) acc[i][j] = z4;

  const u16* Abase = A + (size_t)blockIdx.x * 128 * K;
  const u16* Bbase = B + (size_t)blockIdx.y * 128 * K;

  for (int k0 = 0; k0 < K; k0 += 32) {
#pragma unroll
    for (int q = 0; q < 2; ++q) {
      const int chunk = wave * 2 + q;
      const int row = chunk * 16 + sr;
      __builtin_amdgcn_global_load_lds(
          (__attribute__((address_space(1))) void*)(Abase + (size_t)row * K + k0 + sc),
          (__attribute__((address_space(3))) void*)(sA + chunk * 512), 16, 0, 0);
      __builtin_amdgcn_global_load_lds(
          (__attribute__((address_space(1))) void*)(Bbase + (size_t)row * K + k0 + sc),
          (__attribute__((address_space(3))) void*)(sB + chunk * 512), 16, 0, 0);
    }
    __syncthreads();
    bf16x8 af[4], bfv[4];
#pragma unroll
    for (int i = 0; i < 4; ++i)
      af[i] = *(const bf16x8*)(sA + (wm + i * 16 + fr) * 32 + fk);
#pragma unroll
    for (int j = 0; j < 4; ++j)
      bfv[j] = *(const bf16x8*)(sB + (wn + j * 16 + fr) * 32 + fk);
#pragma unroll
    for (int i = 0; i < 4; ++i)
#pragma unroll
      for (int j = 0; j < 4; ++j)
        acc[i][j] = __builtin_amdgcn_mfma_f32_16x16x32_bf16(af[i], bfv[j], acc[i][j], 0, 0, 0);
    __syncthreads();
  }

#pragma unroll
  for (int i = 0; i < 4; ++i)
#pragma unroll
    for (int j = 0; j < 4; ++j)
#pragma unroll
      for (int r = 0; r < 4; ++r) {
        const int row = blockIdx.x * 128 + wm + i * 16 + quad * 4 + r;
        const int col = blockIdx.y * 128 + wn + j * 16 + fr;
        C[(size_t)row * N + col] = f2bf(acc[i][j][r]);
      }
}

// ---------------- transpose V half of KV into Vt[b,h,d, sigma(N2)] ----------------
// NEW perm matching attn's b128 P-store: within each 128-key chunk,
// pos(k) = (k&15)*8 + 2*(k>>5) + ((k>>4)&1).  P.V invariant under shared perm.
__global__ void transpose_v(const u16* __restrict__ KV, u16* __restrict__ Vt) {
  __shared__ u16 tile[64][66];
  const int t = threadIdx.x;
  const int rb = blockIdx.x * 64;
  const int h = blockIdx.y;
#pragma unroll
  for (int i = 0; i < 16; ++i) {
    int idx = i * 256 + t;
    int r = idx >> 6, c = idx & 63;
    tile[r][c] = KV[(size_t)(rb + r) * 2048 + 1024 + h * 64 + c];
  }
  __syncthreads();
  const int b = blockIdx.x >> 4;
  const int n2b = (blockIdx.x & 15) * 64;   // key base within this b's 1024
#pragma unroll
  for (int i = 0; i < 16; ++i) {
    int idx = i * 256 + t;
    int dd = idx >> 6, n2 = idx & 63;
    int k128 = ((blockIdx.x & 1) << 6) + n2;                       // key within 128-chunk
    int pos = (n2 & 15) * 8 + 2 * (k128 >> 5) + ((k128 >> 4) & 1); // perm position
    Vt[(size_t)((b * 16 + h) * 64 + dd) * 1024 + (n2b & ~127) + pos] = tile[n2][dd];
  }
}

// ---------------- fused flash attention (R4 structure, LDS-op diet) ----------------
// 128 q-rows/block, 128-key chunks, 2 barriers/chunk (R4-proven correctness).
// Deltas vs R4: (1) K fragments loaded ONCE per nt and shared across both
// q-halves (32->16 QK reads); (2) P stored as 4 ds_write_b128 per half in
// perm order pos(k) (16 b32 -> 4 b128), paired with transpose_v's perm.
// 72 b128 LDS ops/wave/chunk (R4: 80 b128 + 32 b32).
__global__ __launch_bounds__(256, 3) void attn_kernel(
    const u16* __restrict__ Q, const u16* __restrict__ KV,
    const u16* __restrict__ Vt, float* __restrict__ Out) {
  __shared__ __align__(16) u16 sK[128 * 72];       // [key][d], pitch 72 (16B rows)
  __shared__ __align__(16) u16 sV[64 * 136];       // [d][perm pos], pitch 136
  __shared__ __align__(16) u16 sP[4][16 * 136];    // per-wave P [q][perm pos]
  // 18432 + 17408 + 17408 = 53248 B -> 3 blocks/CU

  const int t = threadIdx.x;
  const int wave = t >> 6;
  const int lane = t & 63;
  const int g = blockIdx.x & 63;     // (b,h): same mod-64 -> same XCD L2
  const int qt = blockIdx.x >> 6;    // 0..15
  const int b = g >> 4;
  const int h = g & 15;
  const int q0 = qt * 128;
  const int fr = lane & 15;
  const int quad = lane >> 4;

  // Q A-fragments for both 64-row halves (kc-invariant)
  const u16* qbase = Q + (size_t)(b * 2048 + q0 + wave * 16 + fr) * 1024 + h * 64 + quad * 8;
  bf16x8 qa[2][2];
  qa[0][0] = *(const bf16x8*)(qbase);
  qa[0][1] = *(const bf16x8*)(qbase + 32);
  qa[1][0] = *(const bf16x8*)(qbase + (size_t)64 * 1024);
  qa[1][1] = *(const bf16x8*)(qbase + (size_t)64 * 1024 + 32);

  const f32x4 z4 = {0.f, 0.f, 0.f, 0.f};
  float lacc[2][4];
  f32x4 o[2][4];
#pragma unroll
  for (int hh = 0; hh < 2; ++hh)
#pragma unroll
    for (int r = 0; r < 4; ++r) { lacc[hh][r] = 0.f; o[hh][r] = z4; }

  u16* sPw = &sP[wave][0];

  for (int kc = 0; kc < 8; ++kc) {
    // stage K chunk (128x64, pitch 72) and perm-Vt chunk (64x128, pitch 136)
#pragma unroll
    for (int i = 0; i < 4; ++i) {
      int idx = i * 256 + t;
      int r = idx >> 3, c = (idx & 7) * 8;
      *(uint4*)(sK + r * 72 + c) =
          *(const uint4*)(KV + (size_t)(b * 1024 + kc * 128 + r) * 2048 + h * 64 + c);
      int rv = idx >> 4, cv = (idx & 15) * 8;
      *(uint4*)(sV + rv * 136 + cv) =
          *(const uint4*)(Vt + (size_t)((b * 16 + h) * 64 + rv) * 1024 + kc * 128 + cv);
    }
    __syncthreads();

    // QK^T + exp for BOTH halves, K fragments shared.
    // pkd[hh][r] dword np = pk(exp s[2np], exp s[2np+1])
    //   -> P of q-row (quad*4+r), keys {32np+fr (lo), 32np+16+fr (hi)}
    //   -> u16 pos fr*8 + 2np (+1): pos(k) = (k&15)*8 + 2*(k>>5) + ((k>>4)&1)
    u32 pkd[2][4][4];
#pragma unroll
    for (int np = 0; np < 4; ++np) {
      const u16* k0r = sK + ((np * 2) * 16 + fr) * 72 + quad * 8;
      const u16* k1r = sK + ((np * 2 + 1) * 16 + fr) * 72 + quad * 8;
      bf16x8 b0a = *(const bf16x8*)(k0r);
      bf16x8 b0b = *(const bf16x8*)(k0r + 32);
      bf16x8 b1a = *(const bf16x8*)(k1r);
      bf16x8 b1b = *(const bf16x8*)(k1r + 32);
#pragma unroll
      for (int hh = 0; hh < 2; ++hh) {
        f32x4 s0 = __builtin_amdgcn_mfma_f32_16x16x32_bf16(qa[hh][0], b0a, z4, 0, 0, 0);
        s0 = __builtin_amdgcn_mfma_f32_16x16x32_bf16(qa[hh][1], b0b, s0, 0, 0, 0);
        f32x4 s1 = __builtin_amdgcn_mfma_f32_16x16x32_bf16(qa[hh][0], b1a, z4, 0, 0, 0);
        s1 = __builtin_amdgcn_mfma_f32_16x16x32_bf16(qa[hh][1], b1b, s1, 0, 0, 0);
#pragma unroll
        for (int r = 0; r < 4; ++r) {
          float p0 = fast_exp2(s0[r]);
          float p1 = fast_exp2(s1[r]);
          lacc[hh][r] += p0 + p1;
          pkd[hh][r][np] = pk_bf16(p0, p1);
        }
      }
    }

    // per half: P -> LDS as 4 b128 stores (row quad*4+r, cols fr*8..fr*8+7), then PV
#pragma unroll
    for (int hh = 0; hh < 2; ++hh) {
#pragma unroll
      for (int r = 0; r < 4; ++r)
        *(uint4*)(sPw + (quad * 4 + r) * 136 + fr * 8) = *(const uint4*)&pkd[hh][r][0];

      asm volatile("" ::: "memory");  // keep pa reads after P writes (same-wave LDS in order)

#pragma unroll
      for (int ks = 0; ks < 4; ++ks) {
        bf16x8 pa = *(const bf16x8*)(sPw + fr * 136 + ks * 32 + quad * 8);
#pragma unroll
        for (int nt = 0; nt < 4; ++nt) {
          bf16x8 vb = *(const bf16x8*)(sV + (nt * 16 + fr) * 136 + ks * 32 + quad * 8);
          o[hh][nt] = __builtin_amdgcn_mfma_f32_16x16x32_bf16(pa, vb, o[hh][nt], 0, 0, 0);
        }
      }
      asm volatile("" ::: "memory");  // order next half's P writes after these reads
    }
    __syncthreads();   // protect sK/sV for next chunk's staging
  }

  // epilogue: reduce l over the 16 fr lanes, normalize, store
#pragma unroll
  for (int hh = 0; hh < 2; ++hh) {
    float inv[4];
#pragma unroll
    for (int r = 0; r < 4; ++r) {
      float v = lacc[hh][r];
      v += __shfl_xor(v, 1);
      v += __shfl_xor(v, 2);
      v += __shfl_xor(v, 4);
      v += __shfl_xor(v, 8);
      inv[r] = fast_rcp(v);
    }
#pragma unroll
    for (int nt = 0; nt < 4; ++nt)
#pragma unroll
      for (int r = 0; r < 4; ++r) {
        const int row = q0 + hh * 64 + wave * 16 + quad * 4 + r;
        const int col = h * 64 + nt * 16 + fr;
        Out[(size_t)(b * 2048 + row) * 1024 + col] = o[hh][nt][r] * inv[r];
      }
  }
}

// ---------------- launch (R4-proven config & ws layout) ----------------
extern "C" void kernel_launch(void* const* d_in, const int* in_sizes, int n_in,
                              void* d_out, int out_size, void* d_ws, size_t ws_size,
                              hipStream_t stream) {
  (void)in_sizes; (void)n_in; (void)out_size; (void)ws_size;
  const float* x   = (const float*)d_in[0];   // [4,2048,1024]
  const float* y   = (const float*)d_in[1];   // [4,1024,768]
  const int*   msk = (const int*)d_in[2];     // [4,2048]
  const float* Wq  = (const float*)d_in[3];   // [1024,1024]
  const float* Wkv = (const float*)d_in[4];   // [2048,768]
  float* out = (float*)d_out;                 // [4,2048,1024] f32

  char* ws = (char*)d_ws;
  const size_t MB = 1024 * 1024;
  // R4-proven layout; no live overlaps (R3's bug was Qb/KVb overlap — never again).
  u16* Xb   = (u16*)(ws + 0);        // 16 MB [8192][1024] mask-folded (dead after gemm_q)
  u16* Wqb  = (u16*)(ws + 16 * MB);  //  2 MB [1024][1024] * d^-0.5 * log2e
  u16* Yb   = (u16*)(ws + 18 * MB);  //  6 MB [4096][768]
  u16* Wkvb = (u16*)(ws + 24 * MB);  //  3 MB [2048][768]
  u16* Qb   = (u16*)(ws + 27 * MB);  // 16 MB [8192][1024]
  u16* KVb  = (u16*)(ws + 0);        // 16 MB [4096][2048] (over dead Xb, after gemm_q)
  u16* Vtb  = (u16*)(ws + 43 * MB);  //  8 MB [4096][1024]

  cvt_all<<<13824, 256, 0, stream>>>(x, Wq, y, Wkv, msk, Xb, Wqb, Yb, Wkvb);
  gemm_bt<<<dim3(64, 8), 256, 0, stream>>>(Xb, Wqb, Qb, 8192, 1024, 1024);
  gemm_bt<<<dim3(32, 16), 256, 0, stream>>>(Yb, Wkvb, KVb, 4096, 2048, 768);
  transpose_v<<<dim3(64, 16), 256, 0, stream>>>(KVb, Vtb);
  attn_kernel<<<1024, 256, 0, stream>>>(Qb, KVb, Vtb, out);
}